// Round 9
// baseline (412.207 us; speedup 1.0000x reference)
//
#include <hip/hip_runtime.h>
#include <hip/hip_bf16.h>

#define BATCH 16
#define HH 256
#define WW 256
#define NPIX (BATCH*HH*WW)   // 1,048,576
#define NSTEPS 5
#define CBS 40               // padded codebook row stride (u16) — R2-proven spread
#define HS  258              // halo-padded idx row stride
#define HIMG (HS*HS)         // 66564 per batch image

// frags table u16 offsets (k'-order only)
#define W1P 0
#define W2P 9216
#define WTP 10240
#define IDP 11264
#define CBP 12288
#define FRAGS_TOT 20480

using u16 = unsigned short;
using u32 = unsigned int;
using u8  = unsigned char;

typedef __attribute__((ext_vector_type(8))) short bf8_t;   // 8 bf16 = one MFMA A/B frag
typedef __attribute__((ext_vector_type(4))) float f4_t;    // MFMA C/D frag
typedef __attribute__((ext_vector_type(2))) float f2_t;    // v_pk_f32 pair

#define MFMA16 __builtin_amdgcn_mfma_f32_16x16x32_bf16

// DPP min-reduce across a 16-lane row (row_ror:N = 0x120|N) — verified R4/R5
#define DPPMIN(v, CTRL) do { \
    u32 _o = (u32)__builtin_amdgcn_update_dpp((int)(v), (int)(v), (CTRL), 0xF, 0xF, false); \
    (v) = _o < (v) ? _o : (v); } while (0)

// Compiler-only reordering barrier (intra-wave LDS transpose ordering — R6/R8
// validated absmax 0.0). Full memory clobber: hoist global loads manually.
#define LDS_ORDER() asm volatile("" ::: "memory")

__device__ __forceinline__ float bf2f(u32 u) {
    union { u32 i; float f; } v; v.i = u << 16; return v.f;
}
__device__ __forceinline__ u16 f2bf(float f) {
    union { float f; u32 i; } v; v.f = f;
    u32 x = v.i;
    x += 0x7fffu + ((x >> 16) & 1u);
    return (u16)(x >> 16);
}
__device__ __forceinline__ u32 pack2bf(float a, float b) {
    __hip_bfloat162 h2 = __float22bfloat162_rn(float2{a, b});
    union { __hip_bfloat162 h; u32 u; } v; v.h = h2; return v.u;
}
__device__ __forceinline__ float ldin(const void* p, int i, int f32) {
    return f32 ? ((const float*)p)[i] : bf2f(((const u16*)p)[i]);
}
__device__ __forceinline__ u16 ldbf(const void* p, int i, int f32) {
    return f32 ? f2bf(((const float*)p)[i]) : ((const u16*)p)[i];
}
__device__ __forceinline__ int sniff_f32(const void* xraw) {
    const u32* xw = (const u32*)xraw;
    int cnt = 0;
    for (int j = 0; j < 64; j++) {
        u32 w = xw[j];
        float flo = bf2f(w & 0xffffu);
        float a = fabsf(flo);
        if (flo == 0.0f || (a >= 6e-8f && a <= 64.0f)) cnt++;
    }
    return (cnt < 32) ? 1 : 0;
}
// k' channel permutation: k' = 2*(ch&15) + (ch>>4)  <=>  ch = (k'>>1)|((k'&1)<<4)
__device__ __forceinline__ int chperm(int kp) { return (kp >> 1) | ((kp & 1) << 4); }

// ============================ prep ============================
// R25: wf0/stem_bf stored as (m, m+16) float pairs for v_pk_fma_f32 stem.
__global__ void prep_kernel(const void* x,
    const void* stem_w, const void* stem_b, const void* up1_w, const void* up1_b,
    const void* up2_w, const void* up2_b, const void* tau_w, const void* tau_b,
    const void* cb, const void* dec_w, const void* dec_b,
    u16* frags, u16* cb_bf, u16* idxh_a, u16* idxh_b,
    float* cn2, float* cadj, float* decdot, float* wf0,
    float* up1_bf, float* up2_bf, float* tau_bf, float* stem_bf, int* flag)
{
    int f32 = sniff_f32(x);
    int i = blockIdx.x * 256 + threadIdx.x;
    if (i == 0) *flag = f32;
    if (i < 9216) {                        // w1p (k'-order)
        int slot = i >> 9, rem = i & 511, lane = rem >> 3, j = rem & 7;
        int tap = slot >> 1, nt = slot & 1;
        int co = nt*16 + (lane & 15), ci = chperm((lane >> 4)*8 + j);
        frags[W1P + i] = ldbf(up1_w, (co*32+ci)*9 + tap, f32);
        return;
    }
    i -= 9216;
    if (i < 1024) {                        // w2p (k'-order, pre-scaled by -0.25)
        int nt = i >> 9, rem = i & 511, lane = rem >> 3, j = rem & 7;
        int co = nt*16 + (lane & 15), k = chperm((lane >> 4)*8 + j);
        frags[W2P + i] = f2bf(-0.25f * ldin(up2_w, co*32 + k, f32));
        return;
    }
    i -= 1024;
    if (i < 1024) {                        // wtp (k'-order)
        int nt = i >> 9, rem = i & 511, lane = rem >> 3, j = rem & 7;
        int co = nt*16 + (lane & 15), k = chperm((lane >> 4)*8 + j);
        frags[WTP + i] = ldbf(tau_w, co*32 + k, f32);
        return;
    }
    i -= 1024;
    if (i < 1024) {                        // idp (k'-order identity, value -0.25)
        int s = i >> 9, rem = i & 511, lane = rem >> 3, j = rem & 7;
        int colq = lane & 15, quad = lane >> 4;
        int ch = chperm(quad*8 + j);
        frags[IDP + i] = (ch == (colq + s*16)) ? (u16)0xBE80 : (u16)0;
        return;
    }
    i -= 1024;
    if (i < 8192) {                        // cbp (k'-order VQ B-frags)
        int nt = i >> 9, rem = i & 511, lane = rem >> 3, j = rem & 7;
        int code = nt*16 + (lane & 15), c = chperm((lane >> 4)*8 + j);
        frags[CBP + i] = ldbf(cb, code*32 + c, f32);
        return;
    }
    i -= 8192;
    if (i < 257*CBS) {                     // cb_bf: padded rows, k'-order channels
        int row = i / CBS, p = i - row*CBS;
        cb_bf[i] = (p < 32 && row < 256) ? ldbf(cb, row*32 + chperm(p), f32) : (u16)0;
        return;
    }
    i -= 257*CBS;
    if (i < 16448) {                       // halo ring = 256 (zero row) in BOTH bufs
        int bb = i / 1028, r = i - bb*1028;
        int row, colh;
        if (r < 258)      { row = 0;            colh = r; }
        else if (r < 516) { row = 257;          colh = r - 258; }
        else if (r < 774) { row = r - 516 + 1;  colh = 0; }
        else              { row = r - 774 + 1;  colh = 257; }
        int a = bb*HIMG + row*HS + colh;
        idxh_a[a] = 256; idxh_b[a] = 256;
        return;
    }
    i -= 16448;
    if (i < 256) {
        float s = 0.f;
        for (int c = 0; c < 32; c++) { float v = ldin(cb, i*32+c, f32); s += v*v; }
        cn2[i] = 0.5f * s;
        return;
    }
    i -= 256;
    if (i < 256) {                         // cadj = 0.25*cn2 + 0.5
        float s = 0.f;
        for (int c = 0; c < 32; c++) { float v = ldin(cb, i*32+c, f32); s += v*v; }
        cadj[i] = 0.25f * (0.5f * s) + 0.5f;
        return;
    }
    i -= 256;
    if (i < 256) {
        float s = ldin(dec_b, 0, f32);
        for (int c = 0; c < 32; c++) s += ldin(dec_w, c, f32) * ldin(cb, i*32+c, f32);
        decdot[i] = s;
        return;
    }
    i -= 256;
    if (i < 288) {                         // wf0: pair layout (m, m+16) per tap
        int tap = i >> 5, e = i & 31;
        int co = (e >> 1) + (e & 1)*16;
        wf0[i] = ldin(stem_w, co*9 + tap, f32);
        return;
    }
    i -= 288;
    if (i < 32) { up1_bf[i]  = ldin(up1_b, i, f32); return; }
    i -= 32;
    if (i < 32) { up2_bf[i]  = -0.25f * ldin(up2_b, i, f32); return; }
    i -= 32;
    if (i < 32) { tau_bf[i]  = ldin(tau_b, i, f32); return; }
    i -= 32;
    if (i < 32) {                          // stem_bf: pair layout (m, m+16)
        int co = (i >> 1) + (i & 1)*16;
        stem_bf[i] = ldin(stem_b, co, f32);
        return;
    }
}

// ===================== step 1 (stem fused) — R25: pk-f32 stem + bias-C-init ==========
// R18 structure (LDS 47360 B, 3 blocks/CU) + packed-f32 stem conv (pair
// layout matches k' packing) + bias folded into MFMA C-init (channel = lane
// col -> bias is a per-lane f4 broadcast).
__global__ __launch_bounds__(256) void step0_kernel(
    const void* __restrict__ xraw, const int* __restrict__ flagp,
    u16* __restrict__ idx_out,
    const u16* __restrict__ fragsg, const float* __restrict__ cn2,
    const float* __restrict__ up1_b, const float* __restrict__ up2_b,
    const float* __restrict__ tau_b, const float* __restrict__ wf0,
    const float* __restrict__ stem_bf)
{
    __shared__ __align__(16) u16 smem[23680];   // 47360 B
    u16* w1f   = smem;            // 9216 (k')
    u16* w2f   = smem + 9216;     // 1024 (k', pre-scaled -0.25)
    u16* wtf   = smem + 10240;    // 1024 (k')
    u16* tileq = smem + 11264;    // 10368 [quad][py*18+px][8] (k' channel order)
    u16* hzb   = smem + 21632;    // 2048
    float* xs  = (float*)hzb;     // alias (pre-compute phase only)

    const u16* __restrict__ cbg = fragsg + CBP;

    int tid = threadIdx.x;
    int lane = tid & 63, wave = tid >> 6;
    int col = lane & 15, quad = lane >> 4;
    int b = blockIdx.z, x0 = blockIdx.x * 16, y0 = blockIdx.y * 16;

    // identity B-frags (k'-order, pre-scaled -0.25, global/L1)
    bf8_t id0 = *(const bf8_t*)&fragsg[IDP + (0*64+lane)*8];
    bf8_t id1 = *(const bf8_t*)&fragsg[IDP + (1*64+lane)*8];

    // copy k' weight tables: w1p|w2p|wtp = 11264 u16 = 1408 uint4
    {
        const uint4* s4 = (const uint4*)(fragsg + W1P);
        uint4* d4 = (uint4*)smem;
        for (int i = tid; i < 1408; i += 256) d4[i] = s4[i];
    }

    {
        int f32 = *flagp;
        for (int pp = tid; pp < 400; pp += 256) {
            int r = pp / 20, c = pp - r*20;
            int gy = y0 - 2 + r, gx = x0 - 2 + c;
            float v = 0.f;
            if ((unsigned)gy < 256u && (unsigned)gx < 256u)
                v = ldin(xraw, (b << 16) | (gy << 8) | gx, f32);
            xs[pp] = v;
        }
        __syncthreads();
        const f2_t* wb2 = (const f2_t*)stem_bf;   // 16 (m, m+16) pairs
        for (int pp = tid; pp < 324; pp += 256) {
            int r = pp / 18, c = pp - r*18;
            int gy = y0 - 1 + r, gx = x0 - 1 + c;
            uint4 qv[4] = {{0,0,0,0},{0,0,0,0},{0,0,0,0},{0,0,0,0}};
            if ((unsigned)gy < 256u && (unsigned)gx < 256u) {
                f2_t acc2[16];
#pragma unroll
                for (int m = 0; m < 16; m++) acc2[m] = wb2[m];
#pragma unroll
                for (int tap = 0; tap < 9; tap++) {
                    float v = xs[(r + tap/3)*20 + (c + tap%3)];
                    f2_t vv = {v, v};
                    const f2_t* w2 = (const f2_t*)&wf0[tap*32];
#pragma unroll
                    for (int m = 0; m < 16; m++)
                        acc2[m] = __builtin_elementwise_fma(vv, w2[m], acc2[m]);
                }
                // k' packing: word m holds channels (m, m+16)
                u32* ow = (u32*)qv;
                f2_t z2 = {0.f, 0.f};
#pragma unroll
                for (int m = 0; m < 16; m++) {
                    f2_t h2 = __builtin_elementwise_max(acc2[m], z2);
                    ow[m] = pack2bf(h2[0], h2[1]);
                }
            }
#pragma unroll
            for (int q = 0; q < 4; q++)
                *(uint4*)&tileq[(q*324 + pp)*8] = qv[q];
        }
    }
    __syncthreads();

    float cn2adj[16];
#pragma unroll
    for (int nt = 0; nt < 16; nt++) cn2adj[nt] = 0.25f*cn2[nt*16+col] + 0.5f;
    float bu1C0 = up1_b[col], bu1C1 = up1_b[col+16];
    float bu2_0 = up2_b[col], bu2_1 = up2_b[col+16];   // pre-scaled -0.25
    float bt0 = tau_b[col],   bt1 = tau_b[col+16];
    f4_t cb1A = {bu1C0, bu1C0, bu1C0, bu1C0};
    f4_t cb1B = {bu1C1, bu1C1, bu1C1, bu1C1};
    f4_t cb2_0 = {bu2_0, bu2_0, bu2_0, bu2_0};
    f4_t cb2_1 = {bu2_1, bu2_1, bu2_1, bu2_1};
    f4_t cbt0 = {bt0, bt0, bt0, bt0};
    f4_t cbt1 = {bt1, bt1, bt1, bt1};
    u16* hzw = &hzb[wave*512];
    u32* hz32 = (u32*)hzw;
    int wy = wave * 4;
    f4_t kz = {0.f,0.f,0.f,0.f};

    bf8_t rows[4][3];
#pragma unroll
    for (int i = 0; i < 4; i++)
#pragma unroll
        for (int dx = 0; dx < 3; dx++)
            rows[i][dx] = *(const bf8_t*)&tileq[(quad*324 + (wy+i)*18 + col+dx)*8];

#pragma unroll
    for (int rrp = 0; rrp < 2; rrp++) {
        if (rrp) {
#pragma unroll
            for (int dx = 0; dx < 3; dx++) {
                rows[0][dx] = rows[2][dx];
                rows[1][dx] = rows[3][dx];
                rows[2][dx] = *(const bf8_t*)&tileq[(quad*324 + (wy+4)*18 + col+dx)*8];
                rows[3][dx] = *(const bf8_t*)&tileq[(quad*324 + (wy+5)*18 + col+dx)*8];
            }
        }
        // bias-C-init: conv1 accumulators start at up1 bias
        f4_t aA0 = cb1A, aA1 = cb1B, aB0 = cb1A, aB1 = cb1B;
#pragma unroll
        for (int t = 0; t < 9; t++) {
            int dy = t/3, dx = t - dy*3;
            bf8_t wA = *(const bf8_t*)&w1f[((t*2+0)*64 + lane)*8];
            bf8_t wB = *(const bf8_t*)&w1f[((t*2+1)*64 + lane)*8];
            aA0 = MFMA16(rows[dy  ][dx], wA, aA0, 0, 0, 0);
            aA1 = MFMA16(rows[dy  ][dx], wB, aA1, 0, 0, 0);
            aB0 = MFMA16(rows[dy+1][dx], wA, aB0, 0, 0, 0);
            aB1 = MFMA16(rows[dy+1][dx], wB, aB1, 0, 0, 0);
        }
        // h transposes: u32 m-major writes, b128 reads (k' layout)
#pragma unroll
        for (int r = 0; r < 4; r++) {
            int px = quad*4 + r;
            hz32[px*16 + col] = pack2bf(fmaxf(aA0[r], 0.f), fmaxf(aA1[r], 0.f));
        }
        LDS_ORDER();
        bf8_t hA0 = *(const bf8_t*)&hzw[col*32 + quad*8];
        LDS_ORDER();
#pragma unroll
        for (int r = 0; r < 4; r++) {
            int px = quad*4 + r;
            hz32[px*16 + col] = pack2bf(fmaxf(aB0[r], 0.f), fmaxf(aB1[r], 0.f));
        }
        LDS_ORDER();
        bf8_t hA1 = *(const bf8_t*)&hzw[col*32 + quad*8];
        LDS_ORDER();

        bf8_t w20 = *(const bf8_t*)&w2f[(0*64+lane)*8];
        bf8_t w21 = *(const bf8_t*)&w2f[(1*64+lane)*8];
        bf8_t wt0 = *(const bf8_t*)&wtf[(0*64+lane)*8];
        bf8_t wt1 = *(const bf8_t*)&wtf[(1*64+lane)*8];
        bf8_t sA0 = rows[1][1], sA1 = rows[2][1];
        // bias-C-init: d gets up2 bias, t gets tau bias
        f4_t d00 = MFMA16(hA0, w20, cb2_0, 0, 0, 0);
        f4_t d01 = MFMA16(hA0, w21, cb2_1, 0, 0, 0);
        f4_t d10 = MFMA16(hA1, w20, cb2_0, 0, 0, 0);
        f4_t d11 = MFMA16(hA1, w21, cb2_1, 0, 0, 0);
        f4_t t00 = MFMA16(sA0, wt0, cbt0, 0, 0, 0);
        f4_t t01 = MFMA16(sA0, wt1, cbt1, 0, 0, 0);
        f4_t t10 = MFMA16(sA1, wt0, cbt0, 0, 0, 0);
        f4_t t11 = MFMA16(sA1, wt1, cbt1, 0, 0, 0);
        f4_t S0l = MFMA16(sA0, id0, kz, 0, 0, 0);
        f4_t S0h = MFMA16(sA0, id1, kz, 0, 0, 0);
        f4_t S1l = MFMA16(sA1, id0, kz, 0, 0, 0);
        f4_t S1h = MFMA16(sA1, id1, kz, 0, 0, 0);

        // blend + z (row 0) — w2/bias/id pre-scaled by -0.25
#pragma unroll
        for (int r = 0; r < 4; r++) {
            int px = quad*4 + r;
            float dl0 = d00[r], tv0 = t00[r];
            float be0 = 1.0f / (1.0f + __expf(-tv0));
            float dl1 = d01[r], tv1 = t01[r];
            float be1 = 1.0f / (1.0f + __expf(-tv1));
            hz32[px*16 + col] = pack2bf(dl0 + be0*(S0l[r] - dl0),
                                        dl1 + be1*(S0h[r] - dl1));
        }
        LDS_ORDER();
        bf8_t zA0 = *(const bf8_t*)&hzw[col*32 + quad*8];
        LDS_ORDER();
        // blend + z (row 1)
#pragma unroll
        for (int r = 0; r < 4; r++) {
            int px = quad*4 + r;
            float dl0 = d10[r], tv0 = t10[r];
            float be0 = 1.0f / (1.0f + __expf(-tv0));
            float dl1 = d11[r], tv1 = t11[r];
            float be1 = 1.0f / (1.0f + __expf(-tv1));
            hz32[px*16 + col] = pack2bf(dl0 + be0*(S1l[r] - dl0),
                                        dl1 + be1*(S1h[r] - dl1));
        }
        LDS_ORDER();
        bf8_t zA1 = *(const bf8_t*)&hzw[col*32 + quad*8];
        LDS_ORDER();

        // VQ: cbp frag table from global (k', lane-contiguous coalesced b128).
        u32 b0[4], b1[4];
#pragma unroll
        for (int r = 0; r < 4; r++) { b0[r] = 0xFFFFFFFFu; b1[r] = 0xFFFFFFFFu; }
#pragma unroll 4
        for (int nt = 0; nt < 16; nt++) {
            bf8_t cf = *(const bf8_t*)&cbg[(nt*64 + lane)*8];
            f4_t ci = {cn2adj[nt], cn2adj[nt], cn2adj[nt], cn2adj[nt]};
            f4_t s0 = MFMA16(zA0, cf, ci, 0, 0, 0);
            f4_t s1 = MFMA16(zA1, cf, ci, 0, 0, 0);
            u32 code = (u32)(nt*16) | (u32)col;
#pragma unroll
            for (int r = 0; r < 4; r++) {
                u32 k0 = (__builtin_bit_cast(u32, s0[r]) & 0xFFFFFF00u) | code;
                u32 k1 = (__builtin_bit_cast(u32, s1[r]) & 0xFFFFFF00u) | code;
                b0[r] = k0 < b0[r] ? k0 : b0[r];
                b1[r] = k1 < b1[r] ? k1 : b1[r];
            }
        }
#pragma unroll
        for (int r = 0; r < 4; r++) {
            DPPMIN(b0[r], 0x121); DPPMIN(b0[r], 0x122);
            DPPMIN(b0[r], 0x124); DPPMIN(b0[r], 0x128);
            DPPMIN(b1[r], 0x121); DPPMIN(b1[r], 0x122);
            DPPMIN(b1[r], 0x124); DPPMIN(b1[r], 0x128);
        }
        int yr = y0 + wy + rrp*2;
        if (col < 4) {
            int xc = x0 + quad*4 + col + 1;
            idx_out[b*HIMG + (yr+1)*HS + xc] = (u16)(b0[col] & 255u);
            idx_out[b*HIMG + (yr+2)*HS + xc] = (u16)(b1[col] & 255u);
        }
    }
}

// ===================== steps 2..5 — R25: R24 + bias-C-init + kp hoist ==========
// R24 body (halo u16, dx-major dedup, 48208 B LDS). Bias folded into MFMA
// C-init; both th iterations' idx loads hoisted above the first LDS_ORDER
// (the clobber otherwise pins th=1's 18 loads behind th=0's fences).
__global__ __launch_bounds__(256) void step1_kernel(
    const u16* __restrict__ idx_in, u16* __restrict__ idx_out,
    const u16* __restrict__ fragsg, const u16* __restrict__ cbr_g,
    const float* __restrict__ cadj_g,
    const float* __restrict__ up1_b, const float* __restrict__ up2_b,
    const float* __restrict__ tau_b)
{
    __shared__ __align__(16) u16 smem[24104];   // 48208 B
    u16* w1f = smem;                       // 9216 (k'-order)
    u16* w2f = smem + 9216;                // 1024 (pre-scaled -0.25)
    u16* wtf = smem + 10240;               // 1024
    u16* cbr = smem + 11264;               // 10280 (257 x CBS, k'-order)
    float* cadjf = (float*)(smem + 21544); // 256 f32
    u16* hzb = smem + 22056;               // 2048

    int tid = threadIdx.x;
    int lane = tid & 63, wave = tid >> 6;
    int col = lane & 15, quad = lane >> 4;
    int b = blockIdx.z, x0 = blockIdx.x * 16, y0 = blockIdx.y * 32;
    int wy = wave * 4;

    bf8_t id0 = *(const bf8_t*)&fragsg[IDP + (0*64+lane)*8];
    bf8_t id1 = *(const bf8_t*)&fragsg[IDP + (1*64+lane)*8];

    // BOTH th iterations' idx loads, hoisted before any LDS_ORDER
    u32 kps[2][6];
#pragma unroll
    for (int th = 0; th < 2; th++)
#pragma unroll
        for (int tr = 0; tr < 6; tr++) {
            int base = b*HIMG + (y0 + th*16 + wy + tr)*HS + x0 + col;
            kps[th][tr] = (u32)idx_in[base]
                        | ((u32)idx_in[base + 1] << 9)
                        | ((u32)idx_in[base + 2] << 18);
        }

    // tables -> LDS: w1p|w2p|wtp = 1408 uint4, cbr = 1285, cadj = 64
    {
        const uint4* s4 = (const uint4*)(fragsg + W1P);
        uint4* d4 = (uint4*)smem;
        for (int i = tid; i < 1408; i += 256) d4[i] = s4[i];
        const uint4* c4 = (const uint4*)cbr_g;
        uint4* e4 = (uint4*)cbr;
        for (int i = tid; i < 1285; i += 256) e4[i] = c4[i];
        const uint4* a4 = (const uint4*)cadj_g;
        uint4* f4p = (uint4*)cadjf;
        if (tid < 64) f4p[tid] = a4[tid];
    }
    __syncthreads();

    float bu1C0 = up1_b[col], bu1C1 = up1_b[col+16];
    float bu2_0 = up2_b[col], bu2_1 = up2_b[col+16];   // pre-scaled -0.25
    float bt0 = tau_b[col],   bt1 = tau_b[col+16];
    f4_t cb1A = {bu1C0, bu1C0, bu1C0, bu1C0};
    f4_t cb1B = {bu1C1, bu1C1, bu1C1, bu1C1};
    f4_t cb2_0 = {bu2_0, bu2_0, bu2_0, bu2_0};
    f4_t cb2_1 = {bu2_1, bu2_1, bu2_1, bu2_1};
    f4_t cbt0 = {bt0, bt0, bt0, bt0};
    f4_t cbt1 = {bt1, bt1, bt1, bt1};
    u16* hzw = &hzb[wave*512];
    u32* hz32 = (u32*)hzw;
    f4_t kz = {0.f,0.f,0.f,0.f};

#pragma unroll
    for (int th = 0; th < 2; th++) {
        int yb = y0 + th*16;
        const u32* kp = kps[th];

        // bias-C-init: conv1 accumulators start at up1 bias
        f4_t acc[4][2];
#pragma unroll
        for (int r4 = 0; r4 < 4; r4++) { acc[r4][0] = cb1A; acc[r4][1] = cb1B; }
        bf8_t sA[4];
        // dx-major tap loop: gather each distinct (tr,dx) row frag once.
#pragma unroll
        for (int dx = 0; dx < 3; dx++) {
            bf8_t F[6];
#pragma unroll
            for (int tr = 0; tr < 6; tr++) {
                int k = (int)((kp[tr] >> (9*dx)) & 511u);
                F[tr] = *(const bf8_t*)&cbr[k*CBS + quad*8];
            }
            if (dx == 1) {
#pragma unroll
                for (int r4 = 0; r4 < 4; r4++) sA[r4] = F[r4+1];  // t=4 frag
            }
#pragma unroll
            for (int dy = 0; dy < 3; dy++) {
                int t = dy*3 + dx;
                bf8_t wA = *(const bf8_t*)&w1f[((t*2+0)*64 + lane)*8];
                bf8_t wB = *(const bf8_t*)&w1f[((t*2+1)*64 + lane)*8];
#pragma unroll
                for (int r4 = 0; r4 < 4; r4++) {
                    acc[r4][0] = MFMA16(F[r4+dy], wA, acc[r4][0], 0, 0, 0);
                    acc[r4][1] = MFMA16(F[r4+dy], wB, acc[r4][1], 0, 0, 0);
                }
            }
        }

        bf8_t w20 = *(const bf8_t*)&w2f[(0*64+lane)*8];
        bf8_t w21 = *(const bf8_t*)&w2f[(1*64+lane)*8];
        bf8_t wt0 = *(const bf8_t*)&wtf[(0*64+lane)*8];
        bf8_t wt1 = *(const bf8_t*)&wtf[(1*64+lane)*8];

        bf8_t zA[4];
#pragma unroll
        for (int r4 = 0; r4 < 4; r4++) {
#pragma unroll
            for (int r = 0; r < 4; r++) {
                int px = quad*4 + r;
                hz32[px*16 + col] = pack2bf(fmaxf(acc[r4][0][r], 0.f),
                                            fmaxf(acc[r4][1][r], 0.f));
            }
            LDS_ORDER();
            bf8_t hA = *(const bf8_t*)&hzw[col*32 + quad*8];
            LDS_ORDER();
            f4_t d0 = MFMA16(hA, w20, cb2_0, 0, 0, 0);
            f4_t d1 = MFMA16(hA, w21, cb2_1, 0, 0, 0);
            f4_t t0 = MFMA16(sA[r4], wt0, cbt0, 0, 0, 0);
            f4_t t1 = MFMA16(sA[r4], wt1, cbt1, 0, 0, 0);
            f4_t Sl = MFMA16(sA[r4], id0, kz, 0, 0, 0);
            f4_t Sh = MFMA16(sA[r4], id1, kz, 0, 0, 0);
#pragma unroll
            for (int r = 0; r < 4; r++) {
                int px = quad*4 + r;
                float dl0 = d0[r], tv0 = t0[r];
                float be0 = 1.0f / (1.0f + __expf(-tv0));
                float dl1 = d1[r], tv1 = t1[r];
                float be1 = 1.0f / (1.0f + __expf(-tv1));
                hz32[px*16 + col] = pack2bf(dl0 + be0*(Sl[r] - dl0),
                                            dl1 + be1*(Sh[r] - dl1));
            }
            LDS_ORDER();
            zA[r4] = *(const bf8_t*)&hzw[col*32 + quad*8];
            LDS_ORDER();
        }

        u32 bk[4][4];
#pragma unroll
        for (int r4 = 0; r4 < 4; r4++)
#pragma unroll
            for (int r = 0; r < 4; r++) bk[r4][r] = 0xFFFFFFFFu;
#pragma unroll
        for (int nt = 0; nt < 16; nt++) {
            bf8_t cf = *(const bf8_t*)&cbr[(nt*16 + col)*CBS + quad*8];
            float ca = cadjf[nt*16 + col];
            f4_t ci = {ca, ca, ca, ca};
            u32 code = (u32)(nt*16) | (u32)col;
#pragma unroll
            for (int r4 = 0; r4 < 4; r4++) {
                f4_t sc = MFMA16(zA[r4], cf, ci, 0, 0, 0);
#pragma unroll
                for (int r = 0; r < 4; r++) {
                    u32 k0 = (__builtin_bit_cast(u32, sc[r]) & 0xFFFFFF00u) | code;
                    bk[r4][r] = k0 < bk[r4][r] ? k0 : bk[r4][r];
                }
            }
        }
#pragma unroll
        for (int r4 = 0; r4 < 4; r4++) {
#pragma unroll
            for (int r = 0; r < 4; r++) {
                DPPMIN(bk[r4][r], 0x121); DPPMIN(bk[r4][r], 0x122);
                DPPMIN(bk[r4][r], 0x124); DPPMIN(bk[r4][r], 0x128);
            }
            int yr = yb + wy + r4;
            if (col < 4)
                idx_out[b*HIMG + (yr+1)*HS + (x0 + quad*4 + col + 1)] =
                    (u16)(bk[r4][col] & 255u);
        }
    }
}

// ============================ dec ============================
__global__ __launch_bounds__(256) void dec_kernel(const u16* __restrict__ idx,
        const float* __restrict__ decdot, const int* __restrict__ flagp,
        void* __restrict__ out)
{
    int p = blockIdx.x * 256 + threadIdx.x;
    int bb = p >> 16, y = (p >> 8) & 255, xx = p & 255;
    float s = decdot[idx[bb*HIMG + (y+1)*HS + xx + 1]];
    float r = 1.0f / (1.0f + __expf(-s));
    if (*flagp) ((float*)out)[p] = r;
    else        ((u16*)out)[p]   = f2bf(r);
}

extern "C" void kernel_launch(void* const* d_in, const int* in_sizes, int n_in,
                              void* d_out, int out_size, void* d_ws, size_t ws_size,
                              hipStream_t stream)
{
    const void* x      = d_in[0];
    const void* stem_w = d_in[1];
    const void* stem_b = d_in[2];
    const void* up1_w  = d_in[3];
    const void* up1_b  = d_in[4];
    const void* up2_w  = d_in[5];
    const void* up2_b  = d_in[6];
    const void* tau_w  = d_in[7];
    const void* tau_b  = d_in[8];
    const void* cb     = d_in[9];
    const void* dec_w  = d_in[10];
    const void* dec_b  = d_in[11];
    // d_in[12] = n_steps (fixed at 5 by the problem definition)

    char* ws = (char*)d_ws;
    size_t off = 0;
    auto carve = [&](size_t bytes) -> void* {
        void* p = ws + off;
        off += (bytes + 255) & ~(size_t)255;
        return p;
    };
    u16*   idxA    = (u16*)  carve((size_t)BATCH*HIMG*2);  // halo-padded u16
    u16*   idxB    = (u16*)  carve((size_t)BATCH*HIMG*2);
    u16*   frags   = (u16*)  carve(FRAGS_TOT * 2);  // k'-order tables
    u16*   cb_bf   = (u16*)  carve(257*CBS * 2);    // k'-order padded rows
    float* cn2     = (float*)carve(256 * 4);
    float* cadj    = (float*)carve(256 * 4);
    float* decdot  = (float*)carve(256 * 4);
    float* wf0     = (float*)carve(288 * 4);
    float* up1_bf  = (float*)carve(32 * 4);
    float* up2_bf  = (float*)carve(32 * 4);
    float* tau_bf  = (float*)carve(32 * 4);
    float* stem_bf = (float*)carve(32 * 4);
    int*   flag    = (int*)  carve(4);

    prep_kernel<<<190, 256, 0, stream>>>(x, stem_w, stem_b, up1_w, up1_b,
        up2_w, up2_b, tau_w, tau_b, cb, dec_w, dec_b,
        frags, cb_bf, idxA, idxB, cn2, cadj, decdot, wf0,
        up1_bf, up2_bf, tau_bf, stem_bf, flag);

    dim3 g0(WW/16, HH/16, BATCH);
    step0_kernel<<<g0, 256, 0, stream>>>(x, flag, idxA,
        frags, cn2, up1_bf, up2_bf, tau_bf, wf0, stem_bf);
    dim3 g1(WW/16, HH/32, BATCH);
    u16* cur = idxA; u16* nxt = idxB;
    for (int t = 1; t < NSTEPS; t++) {
        step1_kernel<<<g1, 256, 0, stream>>>(cur, nxt, frags, cb_bf, cadj,
                                             up1_bf, up2_bf, tau_bf);
        u16* tmp = cur; cur = nxt; nxt = tmp;
    }
    dec_kernel<<<NPIX/256, 256, 0, stream>>>(cur, decdot, flag, d_out);
}

// Round 10
// 370.477 us; speedup vs baseline: 1.1126x; 1.1126x over previous
//
#include <hip/hip_runtime.h>
#include <hip/hip_bf16.h>

#define BATCH 16
#define HH 256
#define WW 256
#define NPIX (BATCH*HH*WW)   // 1,048,576
#define NSTEPS 5
#define CBS 40               // padded codebook row stride (u16) — R2-proven spread
#define HS  258              // halo-padded idx row stride
#define HIMG (HS*HS)         // 66564 per batch image

// frags table u16 offsets (k'-order only)
#define W1P 0
#define W2P 9216
#define WTP 10240
#define IDP 11264
#define CBP 12288
#define FRAGS_TOT 20480

using u16 = unsigned short;
using u32 = unsigned int;
using u8  = unsigned char;

typedef __attribute__((ext_vector_type(8))) short bf8_t;   // 8 bf16 = one MFMA A/B frag
typedef __attribute__((ext_vector_type(4))) float f4_t;    // MFMA C/D frag

#define MFMA16 __builtin_amdgcn_mfma_f32_16x16x32_bf16

// DPP min-reduce across a 16-lane row (row_ror:N = 0x120|N) — verified R4/R5
#define DPPMIN(v, CTRL) do { \
    u32 _o = (u32)__builtin_amdgcn_update_dpp((int)(v), (int)(v), (CTRL), 0xF, 0xF, false); \
    (v) = _o < (v) ? _o : (v); } while (0)

// Compiler-only reordering barrier (intra-wave LDS transpose ordering — R6/R8
// validated absmax 0.0). Full memory clobber: hoist global loads manually.
#define LDS_ORDER() asm volatile("" ::: "memory")

__device__ __forceinline__ float bf2f(u32 u) {
    union { u32 i; float f; } v; v.i = u << 16; return v.f;
}
__device__ __forceinline__ u16 f2bf(float f) {
    union { float f; u32 i; } v; v.f = f;
    u32 x = v.i;
    x += 0x7fffu + ((x >> 16) & 1u);
    return (u16)(x >> 16);
}
__device__ __forceinline__ u32 pack2bf(float a, float b) {
    __hip_bfloat162 h2 = __float22bfloat162_rn(float2{a, b});
    union { __hip_bfloat162 h; u32 u; } v; v.h = h2; return v.u;
}
__device__ __forceinline__ float ldin(const void* p, int i, int f32) {
    return f32 ? ((const float*)p)[i] : bf2f(((const u16*)p)[i]);
}
__device__ __forceinline__ u16 ldbf(const void* p, int i, int f32) {
    return f32 ? f2bf(((const float*)p)[i]) : ((const u16*)p)[i];
}
__device__ __forceinline__ int sniff_f32(const void* xraw) {
    const u32* xw = (const u32*)xraw;
    int cnt = 0;
    for (int j = 0; j < 64; j++) {
        u32 w = xw[j];
        float flo = bf2f(w & 0xffffu);
        float a = fabsf(flo);
        if (flo == 0.0f || (a >= 6e-8f && a <= 64.0f)) cnt++;
    }
    return (cnt < 32) ? 1 : 0;
}
// k' channel permutation: k' = 2*(ch&15) + (ch>>4)  <=>  ch = (k'>>1)|((k'&1)<<4)
__device__ __forceinline__ int chperm(int kp) { return (kp >> 1) | ((kp & 1) << 4); }

// ============================ prep ============================
// R26 = R24 prep (halo ring init; plain wf0/stem_bf layout).
__global__ void prep_kernel(const void* x,
    const void* stem_w, const void* stem_b, const void* up1_w, const void* up1_b,
    const void* up2_w, const void* up2_b, const void* tau_w, const void* tau_b,
    const void* cb, const void* dec_w, const void* dec_b,
    u16* frags, u16* cb_bf, u16* idxh_a, u16* idxh_b,
    float* cn2, float* cadj, float* decdot, float* wf0,
    float* up1_bf, float* up2_bf, float* tau_bf, float* stem_bf, int* flag)
{
    int f32 = sniff_f32(x);
    int i = blockIdx.x * 256 + threadIdx.x;
    if (i == 0) *flag = f32;
    if (i < 9216) {                        // w1p (k'-order)
        int slot = i >> 9, rem = i & 511, lane = rem >> 3, j = rem & 7;
        int tap = slot >> 1, nt = slot & 1;
        int co = nt*16 + (lane & 15), ci = chperm((lane >> 4)*8 + j);
        frags[W1P + i] = ldbf(up1_w, (co*32+ci)*9 + tap, f32);
        return;
    }
    i -= 9216;
    if (i < 1024) {                        // w2p (k'-order, pre-scaled by -0.25)
        int nt = i >> 9, rem = i & 511, lane = rem >> 3, j = rem & 7;
        int co = nt*16 + (lane & 15), k = chperm((lane >> 4)*8 + j);
        frags[W2P + i] = f2bf(-0.25f * ldin(up2_w, co*32 + k, f32));
        return;
    }
    i -= 1024;
    if (i < 1024) {                        // wtp (k'-order)
        int nt = i >> 9, rem = i & 511, lane = rem >> 3, j = rem & 7;
        int co = nt*16 + (lane & 15), k = chperm((lane >> 4)*8 + j);
        frags[WTP + i] = ldbf(tau_w, co*32 + k, f32);
        return;
    }
    i -= 1024;
    if (i < 1024) {                        // idp (k'-order identity, value -0.25)
        int s = i >> 9, rem = i & 511, lane = rem >> 3, j = rem & 7;
        int colq = lane & 15, quad = lane >> 4;
        int ch = chperm(quad*8 + j);
        frags[IDP + i] = (ch == (colq + s*16)) ? (u16)0xBE80 : (u16)0;
        return;
    }
    i -= 1024;
    if (i < 8192) {                        // cbp (k'-order VQ B-frags)
        int nt = i >> 9, rem = i & 511, lane = rem >> 3, j = rem & 7;
        int code = nt*16 + (lane & 15), c = chperm((lane >> 4)*8 + j);
        frags[CBP + i] = ldbf(cb, code*32 + c, f32);
        return;
    }
    i -= 8192;
    if (i < 257*CBS) {                     // cb_bf: padded rows, k'-order channels
        int row = i / CBS, p = i - row*CBS;
        cb_bf[i] = (p < 32 && row < 256) ? ldbf(cb, row*32 + chperm(p), f32) : (u16)0;
        return;
    }
    i -= 257*CBS;
    if (i < 16448) {                       // halo ring = 256 (zero row) in BOTH bufs
        int bb = i / 1028, r = i - bb*1028;
        int row, colh;
        if (r < 258)      { row = 0;            colh = r; }
        else if (r < 516) { row = 257;          colh = r - 258; }
        else if (r < 774) { row = r - 516 + 1;  colh = 0; }
        else              { row = r - 774 + 1;  colh = 257; }
        int a = bb*HIMG + row*HS + colh;
        idxh_a[a] = 256; idxh_b[a] = 256;
        return;
    }
    i -= 16448;
    if (i < 256) {
        float s = 0.f;
        for (int c = 0; c < 32; c++) { float v = ldin(cb, i*32+c, f32); s += v*v; }
        cn2[i] = 0.5f * s;
        return;
    }
    i -= 256;
    if (i < 256) {                         // cadj = 0.25*cn2 + 0.5
        float s = 0.f;
        for (int c = 0; c < 32; c++) { float v = ldin(cb, i*32+c, f32); s += v*v; }
        cadj[i] = 0.25f * (0.5f * s) + 0.5f;
        return;
    }
    i -= 256;
    if (i < 256) {
        float s = ldin(dec_b, 0, f32);
        for (int c = 0; c < 32; c++) s += ldin(dec_w, c, f32) * ldin(cb, i*32+c, f32);
        decdot[i] = s;
        return;
    }
    i -= 256;
    if (i < 288) {
        int tap = i >> 5, co = i & 31;
        wf0[i] = ldin(stem_w, co*9 + tap, f32);
        return;
    }
    i -= 288;
    if (i < 32) { up1_bf[i]  = ldin(up1_b, i, f32); return; }
    i -= 32;
    if (i < 32) { up2_bf[i]  = -0.25f * ldin(up2_b, i, f32); return; }
    i -= 32;
    if (i < 32) { tau_bf[i]  = ldin(tau_b, i, f32); return; }
    i -= 32;
    if (i < 32) { stem_bf[i] = ldin(stem_b, i, f32); return; }
}

// ===================== step 1 (stem fused) — R26 = R24 step0 verbatim ==========
// Proven ~94us / absmax 0.0 (R8). R9's pk-f32 stem + bias-C-init reverted:
// they raised VGPR 84->104 and cost 18us (occupancy 29->21%).
__global__ __launch_bounds__(256) void step0_kernel(
    const void* __restrict__ xraw, const int* __restrict__ flagp,
    u16* __restrict__ idx_out,
    const u16* __restrict__ fragsg, const float* __restrict__ cn2,
    const float* __restrict__ up1_b, const float* __restrict__ up2_b,
    const float* __restrict__ tau_b, const float* __restrict__ wf0,
    const float* __restrict__ stem_bf)
{
    __shared__ __align__(16) u16 smem[23680];   // 47360 B
    u16* w1f   = smem;            // 9216 (k')
    u16* w2f   = smem + 9216;     // 1024 (k', pre-scaled -0.25)
    u16* wtf   = smem + 10240;    // 1024 (k')
    u16* tileq = smem + 11264;    // 10368 [quad][py*18+px][8] (k' channel order)
    u16* hzb   = smem + 21632;    // 2048
    float* xs  = (float*)hzb;     // alias (pre-compute phase only)

    const u16* __restrict__ cbg = fragsg + CBP;

    int tid = threadIdx.x;
    int lane = tid & 63, wave = tid >> 6;
    int col = lane & 15, quad = lane >> 4;
    int b = blockIdx.z, x0 = blockIdx.x * 16, y0 = blockIdx.y * 16;

    // identity B-frags (k'-order, pre-scaled -0.25, global/L1)
    bf8_t id0 = *(const bf8_t*)&fragsg[IDP + (0*64+lane)*8];
    bf8_t id1 = *(const bf8_t*)&fragsg[IDP + (1*64+lane)*8];

    // copy k' weight tables: w1p|w2p|wtp = 11264 u16 = 1408 uint4
    {
        const uint4* s4 = (const uint4*)(fragsg + W1P);
        uint4* d4 = (uint4*)smem;
        for (int i = tid; i < 1408; i += 256) d4[i] = s4[i];
    }

    {
        int f32 = *flagp;
        for (int pp = tid; pp < 400; pp += 256) {
            int r = pp / 20, c = pp - r*20;
            int gy = y0 - 2 + r, gx = x0 - 2 + c;
            float v = 0.f;
            if ((unsigned)gy < 256u && (unsigned)gx < 256u)
                v = ldin(xraw, (b << 16) | (gy << 8) | gx, f32);
            xs[pp] = v;
        }
        __syncthreads();
        for (int pp = tid; pp < 324; pp += 256) {
            int r = pp / 18, c = pp - r*18;
            int gy = y0 - 1 + r, gx = x0 - 1 + c;
            uint4 qv[4] = {{0,0,0,0},{0,0,0,0},{0,0,0,0},{0,0,0,0}};
            if ((unsigned)gy < 256u && (unsigned)gx < 256u) {
                float acc[32];
#pragma unroll
                for (int co = 0; co < 32; co++) acc[co] = stem_bf[co];
#pragma unroll
                for (int tap = 0; tap < 9; tap++) {
                    float v = xs[(r + tap/3)*20 + (c + tap%3)];
                    const float* w = &wf0[tap*32];
#pragma unroll
                    for (int co = 0; co < 32; co++) acc[co] = fmaf(v, w[co], acc[co]);
                }
                // k' packing: word m holds channels (m, m+16)
                u32* ow = (u32*)qv;
#pragma unroll
                for (int m = 0; m < 16; m++)
                    ow[m] = pack2bf(fmaxf(acc[m], 0.f), fmaxf(acc[m+16], 0.f));
            }
#pragma unroll
            for (int q = 0; q < 4; q++)
                *(uint4*)&tileq[(q*324 + pp)*8] = qv[q];
        }
    }
    __syncthreads();

    float cn2adj[16];
#pragma unroll
    for (int nt = 0; nt < 16; nt++) cn2adj[nt] = 0.25f*cn2[nt*16+col] + 0.5f;
    float bu1C0 = up1_b[col], bu1C1 = up1_b[col+16];
    float bu2_0 = up2_b[col], bu2_1 = up2_b[col+16];   // pre-scaled -0.25
    float bt0 = tau_b[col],   bt1 = tau_b[col+16];
    u16* hzw = &hzb[wave*512];
    u32* hz32 = (u32*)hzw;
    int wy = wave * 4;
    f4_t kz = {0.f,0.f,0.f,0.f};

    bf8_t rows[4][3];
#pragma unroll
    for (int i = 0; i < 4; i++)
#pragma unroll
        for (int dx = 0; dx < 3; dx++)
            rows[i][dx] = *(const bf8_t*)&tileq[(quad*324 + (wy+i)*18 + col+dx)*8];

#pragma unroll
    for (int rrp = 0; rrp < 2; rrp++) {
        if (rrp) {
#pragma unroll
            for (int dx = 0; dx < 3; dx++) {
                rows[0][dx] = rows[2][dx];
                rows[1][dx] = rows[3][dx];
                rows[2][dx] = *(const bf8_t*)&tileq[(quad*324 + (wy+4)*18 + col+dx)*8];
                rows[3][dx] = *(const bf8_t*)&tileq[(quad*324 + (wy+5)*18 + col+dx)*8];
            }
        }
        f4_t aA0 = kz, aA1 = kz, aB0 = kz, aB1 = kz;
#pragma unroll
        for (int t = 0; t < 9; t++) {
            int dy = t/3, dx = t - dy*3;
            bf8_t wA = *(const bf8_t*)&w1f[((t*2+0)*64 + lane)*8];
            bf8_t wB = *(const bf8_t*)&w1f[((t*2+1)*64 + lane)*8];
            aA0 = MFMA16(rows[dy  ][dx], wA, aA0, 0, 0, 0);
            aA1 = MFMA16(rows[dy  ][dx], wB, aA1, 0, 0, 0);
            aB0 = MFMA16(rows[dy+1][dx], wA, aB0, 0, 0, 0);
            aB1 = MFMA16(rows[dy+1][dx], wB, aB1, 0, 0, 0);
        }
        // h transposes: u32 m-major writes, b128 reads (k' layout)
#pragma unroll
        for (int r = 0; r < 4; r++) {
            int px = quad*4 + r;
            hz32[px*16 + col] = pack2bf(fmaxf(aA0[r] + bu1C0, 0.f),
                                        fmaxf(aA1[r] + bu1C1, 0.f));
        }
        LDS_ORDER();
        bf8_t hA0 = *(const bf8_t*)&hzw[col*32 + quad*8];
        LDS_ORDER();
#pragma unroll
        for (int r = 0; r < 4; r++) {
            int px = quad*4 + r;
            hz32[px*16 + col] = pack2bf(fmaxf(aB0[r] + bu1C0, 0.f),
                                        fmaxf(aB1[r] + bu1C1, 0.f));
        }
        LDS_ORDER();
        bf8_t hA1 = *(const bf8_t*)&hzw[col*32 + quad*8];
        LDS_ORDER();

        bf8_t w20 = *(const bf8_t*)&w2f[(0*64+lane)*8];
        bf8_t w21 = *(const bf8_t*)&w2f[(1*64+lane)*8];
        bf8_t wt0 = *(const bf8_t*)&wtf[(0*64+lane)*8];
        bf8_t wt1 = *(const bf8_t*)&wtf[(1*64+lane)*8];
        bf8_t sA0 = rows[1][1], sA1 = rows[2][1];
        f4_t d00 = MFMA16(hA0, w20, kz, 0, 0, 0);
        f4_t d01 = MFMA16(hA0, w21, kz, 0, 0, 0);
        f4_t d10 = MFMA16(hA1, w20, kz, 0, 0, 0);
        f4_t d11 = MFMA16(hA1, w21, kz, 0, 0, 0);
        f4_t t00 = MFMA16(sA0, wt0, kz, 0, 0, 0);
        f4_t t01 = MFMA16(sA0, wt1, kz, 0, 0, 0);
        f4_t t10 = MFMA16(sA1, wt0, kz, 0, 0, 0);
        f4_t t11 = MFMA16(sA1, wt1, kz, 0, 0, 0);
        f4_t S0l = MFMA16(sA0, id0, kz, 0, 0, 0);
        f4_t S0h = MFMA16(sA0, id1, kz, 0, 0, 0);
        f4_t S1l = MFMA16(sA1, id0, kz, 0, 0, 0);
        f4_t S1h = MFMA16(sA1, id1, kz, 0, 0, 0);

        // blend + z (row 0) — w2/bias/id pre-scaled by -0.25
#pragma unroll
        for (int r = 0; r < 4; r++) {
            int px = quad*4 + r;
            float dl0 = d00[r] + bu2_0, tv0 = t00[r] + bt0;
            float be0 = 1.0f / (1.0f + __expf(-tv0));
            float dl1 = d01[r] + bu2_1, tv1 = t01[r] + bt1;
            float be1 = 1.0f / (1.0f + __expf(-tv1));
            hz32[px*16 + col] = pack2bf(dl0 + be0*(S0l[r] - dl0),
                                        dl1 + be1*(S0h[r] - dl1));
        }
        LDS_ORDER();
        bf8_t zA0 = *(const bf8_t*)&hzw[col*32 + quad*8];
        LDS_ORDER();
        // blend + z (row 1)
#pragma unroll
        for (int r = 0; r < 4; r++) {
            int px = quad*4 + r;
            float dl0 = d10[r] + bu2_0, tv0 = t10[r] + bt0;
            float be0 = 1.0f / (1.0f + __expf(-tv0));
            float dl1 = d11[r] + bu2_1, tv1 = t11[r] + bt1;
            float be1 = 1.0f / (1.0f + __expf(-tv1));
            hz32[px*16 + col] = pack2bf(dl0 + be0*(S1l[r] - dl0),
                                        dl1 + be1*(S1h[r] - dl1));
        }
        LDS_ORDER();
        bf8_t zA1 = *(const bf8_t*)&hzw[col*32 + quad*8];
        LDS_ORDER();

        // VQ: cbp frag table from global (k', lane-contiguous coalesced b128).
        u32 b0[4], b1[4];
#pragma unroll
        for (int r = 0; r < 4; r++) { b0[r] = 0xFFFFFFFFu; b1[r] = 0xFFFFFFFFu; }
#pragma unroll 4
        for (int nt = 0; nt < 16; nt++) {
            bf8_t cf = *(const bf8_t*)&cbg[(nt*64 + lane)*8];
            f4_t ci = {cn2adj[nt], cn2adj[nt], cn2adj[nt], cn2adj[nt]};
            f4_t s0 = MFMA16(zA0, cf, ci, 0, 0, 0);
            f4_t s1 = MFMA16(zA1, cf, ci, 0, 0, 0);
            u32 code = (u32)(nt*16) | (u32)col;
#pragma unroll
            for (int r = 0; r < 4; r++) {
                u32 k0 = (__builtin_bit_cast(u32, s0[r]) & 0xFFFFFF00u) | code;
                u32 k1 = (__builtin_bit_cast(u32, s1[r]) & 0xFFFFFF00u) | code;
                b0[r] = k0 < b0[r] ? k0 : b0[r];
                b1[r] = k1 < b1[r] ? k1 : b1[r];
            }
        }
#pragma unroll
        for (int r = 0; r < 4; r++) {
            DPPMIN(b0[r], 0x121); DPPMIN(b0[r], 0x122);
            DPPMIN(b0[r], 0x124); DPPMIN(b0[r], 0x128);
            DPPMIN(b1[r], 0x121); DPPMIN(b1[r], 0x122);
            DPPMIN(b1[r], 0x124); DPPMIN(b1[r], 0x128);
        }
        int yr = y0 + wy + rrp*2;
        if (col < 4) {
            int xc = x0 + quad*4 + col + 1;
            idx_out[b*HIMG + (yr+1)*HS + xc] = (u16)(b0[col] & 255u);
            idx_out[b*HIMG + (yr+2)*HS + xc] = (u16)(b1[col] & 255u);
        }
    }
}

// ===================== steps 2..5 — R26: R24 body, 8-wave blocks ==========
// R24 body byte-for-byte (halo u16 loads, dx-major dedup, scalar bias adds),
// re-partitioned: 512 threads / 8 waves cover the full 32-row tile in ONE
// pass (th loop removed). Same 46KB table copy now feeds 8 waves instead of
// 4 -> LDS 52304 B allows 3 blocks/CU = 24 waves/CU (6/SIMD if VGPR<=85),
// doubling latency-hiding vs R24's 12 waves/CU. Per-wave serial chain halves.
__global__ __launch_bounds__(512) void step1_kernel(
    const u16* __restrict__ idx_in, u16* __restrict__ idx_out,
    const u16* __restrict__ fragsg, const u16* __restrict__ cbr_g,
    const float* __restrict__ cadj_g,
    const float* __restrict__ up1_b, const float* __restrict__ up2_b,
    const float* __restrict__ tau_b)
{
    __shared__ __align__(16) u16 smem[26152];   // 52304 B
    u16* w1f = smem;                       // 9216 (k'-order)
    u16* w2f = smem + 9216;                // 1024 (pre-scaled -0.25)
    u16* wtf = smem + 10240;               // 1024
    u16* cbr = smem + 11264;               // 10280 (257 x CBS, k'-order)
    float* cadjf = (float*)(smem + 21544); // 256 f32
    u16* hzb = smem + 22056;               // 4096 (8 waves x 512 u16)

    int tid = threadIdx.x;
    int lane = tid & 63, wave = tid >> 6;   // 0..7
    int col = lane & 15, quad = lane >> 4;
    int b = blockIdx.z, x0 = blockIdx.x * 16, y0 = blockIdx.y * 32;
    int wy = wave * 4;                      // 0..28

    bf8_t id0 = *(const bf8_t*)&fragsg[IDP + (0*64+lane)*8];
    bf8_t id1 = *(const bf8_t*)&fragsg[IDP + (1*64+lane)*8];

    // idx loads issued early: in flight during the table copy + barrier
    u32 kp[6];
#pragma unroll
    for (int tr = 0; tr < 6; tr++) {
        int base = b*HIMG + (y0 + wy + tr)*HS + x0 + col;
        kp[tr] = (u32)idx_in[base]
               | ((u32)idx_in[base + 1] << 9)
               | ((u32)idx_in[base + 2] << 18);
    }

    // tables -> LDS: w1p|w2p|wtp = 1408 uint4, cbr = 1285, cadj = 64
    {
        const uint4* s4 = (const uint4*)(fragsg + W1P);
        uint4* d4 = (uint4*)smem;
        for (int i = tid; i < 1408; i += 512) d4[i] = s4[i];
        const uint4* c4 = (const uint4*)cbr_g;
        uint4* e4 = (uint4*)cbr;
        for (int i = tid; i < 1285; i += 512) e4[i] = c4[i];
        const uint4* a4 = (const uint4*)cadj_g;
        uint4* f4p = (uint4*)cadjf;
        if (tid < 64) f4p[tid] = a4[tid];
    }
    __syncthreads();

    float bu1C0 = up1_b[col], bu1C1 = up1_b[col+16];
    float bu2_0 = up2_b[col], bu2_1 = up2_b[col+16];   // pre-scaled -0.25
    float bt0 = tau_b[col],   bt1 = tau_b[col+16];
    u16* hzw = &hzb[wave*512];
    u32* hz32 = (u32*)hzw;
    f4_t kz = {0.f,0.f,0.f,0.f};

    f4_t acc[4][2];
#pragma unroll
    for (int r4 = 0; r4 < 4; r4++) { acc[r4][0] = kz; acc[r4][1] = kz; }
    bf8_t sA[4];
    // dx-major tap loop: gather each distinct (tr,dx) row frag once.
#pragma unroll
    for (int dx = 0; dx < 3; dx++) {
        bf8_t F[6];
#pragma unroll
        for (int tr = 0; tr < 6; tr++) {
            int k = (int)((kp[tr] >> (9*dx)) & 511u);
            F[tr] = *(const bf8_t*)&cbr[k*CBS + quad*8];
        }
        if (dx == 1) {
#pragma unroll
            for (int r4 = 0; r4 < 4; r4++) sA[r4] = F[r4+1];  // t=4 frag
        }
#pragma unroll
        for (int dy = 0; dy < 3; dy++) {
            int t = dy*3 + dx;
            bf8_t wA = *(const bf8_t*)&w1f[((t*2+0)*64 + lane)*8];
            bf8_t wB = *(const bf8_t*)&w1f[((t*2+1)*64 + lane)*8];
#pragma unroll
            for (int r4 = 0; r4 < 4; r4++) {
                acc[r4][0] = MFMA16(F[r4+dy], wA, acc[r4][0], 0, 0, 0);
                acc[r4][1] = MFMA16(F[r4+dy], wB, acc[r4][1], 0, 0, 0);
            }
        }
    }

    bf8_t w20 = *(const bf8_t*)&w2f[(0*64+lane)*8];
    bf8_t w21 = *(const bf8_t*)&w2f[(1*64+lane)*8];
    bf8_t wt0 = *(const bf8_t*)&wtf[(0*64+lane)*8];
    bf8_t wt1 = *(const bf8_t*)&wtf[(1*64+lane)*8];

    bf8_t zA[4];
#pragma unroll
    for (int r4 = 0; r4 < 4; r4++) {
#pragma unroll
        for (int r = 0; r < 4; r++) {
            int px = quad*4 + r;
            hz32[px*16 + col] = pack2bf(fmaxf(acc[r4][0][r] + bu1C0, 0.f),
                                        fmaxf(acc[r4][1][r] + bu1C1, 0.f));
        }
        LDS_ORDER();
        bf8_t hA = *(const bf8_t*)&hzw[col*32 + quad*8];
        LDS_ORDER();
        f4_t d0 = MFMA16(hA, w20, kz, 0, 0, 0);
        f4_t d1 = MFMA16(hA, w21, kz, 0, 0, 0);
        f4_t t0 = MFMA16(sA[r4], wt0, kz, 0, 0, 0);
        f4_t t1 = MFMA16(sA[r4], wt1, kz, 0, 0, 0);
        f4_t Sl = MFMA16(sA[r4], id0, kz, 0, 0, 0);
        f4_t Sh = MFMA16(sA[r4], id1, kz, 0, 0, 0);
#pragma unroll
        for (int r = 0; r < 4; r++) {
            int px = quad*4 + r;
            float dl0 = d0[r] + bu2_0, tv0 = t0[r] + bt0;
            float be0 = 1.0f / (1.0f + __expf(-tv0));
            float dl1 = d1[r] + bu2_1, tv1 = t1[r] + bt1;
            float be1 = 1.0f / (1.0f + __expf(-tv1));
            hz32[px*16 + col] = pack2bf(dl0 + be0*(Sl[r] - dl0),
                                        dl1 + be1*(Sh[r] - dl1));
        }
        LDS_ORDER();
        zA[r4] = *(const bf8_t*)&hzw[col*32 + quad*8];
        LDS_ORDER();
    }

    u32 bk[4][4];
#pragma unroll
    for (int r4 = 0; r4 < 4; r4++)
#pragma unroll
        for (int r = 0; r < 4; r++) bk[r4][r] = 0xFFFFFFFFu;
#pragma unroll
    for (int nt = 0; nt < 16; nt++) {
        bf8_t cf = *(const bf8_t*)&cbr[(nt*16 + col)*CBS + quad*8];
        float ca = cadjf[nt*16 + col];
        f4_t ci = {ca, ca, ca, ca};
        u32 code = (u32)(nt*16) | (u32)col;
#pragma unroll
        for (int r4 = 0; r4 < 4; r4++) {
            f4_t sc = MFMA16(zA[r4], cf, ci, 0, 0, 0);
#pragma unroll
            for (int r = 0; r < 4; r++) {
                u32 k0 = (__builtin_bit_cast(u32, sc[r]) & 0xFFFFFF00u) | code;
                bk[r4][r] = k0 < bk[r4][r] ? k0 : bk[r4][r];
            }
        }
    }
#pragma unroll
    for (int r4 = 0; r4 < 4; r4++) {
#pragma unroll
        for (int r = 0; r < 4; r++) {
            DPPMIN(bk[r4][r], 0x121); DPPMIN(bk[r4][r], 0x122);
            DPPMIN(bk[r4][r], 0x124); DPPMIN(bk[r4][r], 0x128);
        }
        int yr = y0 + wy + r4;
        if (col < 4)
            idx_out[b*HIMG + (yr+1)*HS + (x0 + quad*4 + col + 1)] =
                (u16)(bk[r4][col] & 255u);
    }
}

// ============================ dec ============================
__global__ __launch_bounds__(256) void dec_kernel(const u16* __restrict__ idx,
        const float* __restrict__ decdot, const int* __restrict__ flagp,
        void* __restrict__ out)
{
    int p = blockIdx.x * 256 + threadIdx.x;
    int bb = p >> 16, y = (p >> 8) & 255, xx = p & 255;
    float s = decdot[idx[bb*HIMG + (y+1)*HS + xx + 1]];
    float r = 1.0f / (1.0f + __expf(-s));
    if (*flagp) ((float*)out)[p] = r;
    else        ((u16*)out)[p]   = f2bf(r);
}

extern "C" void kernel_launch(void* const* d_in, const int* in_sizes, int n_in,
                              void* d_out, int out_size, void* d_ws, size_t ws_size,
                              hipStream_t stream)
{
    const void* x      = d_in[0];
    const void* stem_w = d_in[1];
    const void* stem_b = d_in[2];
    const void* up1_w  = d_in[3];
    const void* up1_b  = d_in[4];
    const void* up2_w  = d_in[5];
    const void* up2_b  = d_in[6];
    const void* tau_w  = d_in[7];
    const void* tau_b  = d_in[8];
    const void* cb     = d_in[9];
    const void* dec_w  = d_in[10];
    const void* dec_b  = d_in[11];
    // d_in[12] = n_steps (fixed at 5 by the problem definition)

    char* ws = (char*)d_ws;
    size_t off = 0;
    auto carve = [&](size_t bytes) -> void* {
        void* p = ws + off;
        off += (bytes + 255) & ~(size_t)255;
        return p;
    };
    u16*   idxA    = (u16*)  carve((size_t)BATCH*HIMG*2);  // halo-padded u16
    u16*   idxB    = (u16*)  carve((size_t)BATCH*HIMG*2);
    u16*   frags   = (u16*)  carve(FRAGS_TOT * 2);  // k'-order tables
    u16*   cb_bf   = (u16*)  carve(257*CBS * 2);    // k'-order padded rows
    float* cn2     = (float*)carve(256 * 4);
    float* cadj    = (float*)carve(256 * 4);
    float* decdot  = (float*)carve(256 * 4);
    float* wf0     = (float*)carve(288 * 4);
    float* up1_bf  = (float*)carve(32 * 4);
    float* up2_bf  = (float*)carve(32 * 4);
    float* tau_bf  = (float*)carve(32 * 4);
    float* stem_bf = (float*)carve(32 * 4);
    int*   flag    = (int*)  carve(4);

    prep_kernel<<<190, 256, 0, stream>>>(x, stem_w, stem_b, up1_w, up1_b,
        up2_w, up2_b, tau_w, tau_b, cb, dec_w, dec_b,
        frags, cb_bf, idxA, idxB, cn2, cadj, decdot, wf0,
        up1_bf, up2_bf, tau_bf, stem_bf, flag);

    dim3 g0(WW/16, HH/16, BATCH);
    step0_kernel<<<g0, 256, 0, stream>>>(x, flag, idxA,
        frags, cn2, up1_bf, up2_bf, tau_bf, wf0, stem_bf);
    dim3 g1(WW/16, HH/32, BATCH);
    u16* cur = idxA; u16* nxt = idxB;
    for (int t = 1; t < NSTEPS; t++) {
        step1_kernel<<<g1, 512, 0, stream>>>(cur, nxt, frags, cb_bf, cadj,
                                             up1_bf, up2_bf, tau_bf);
        u16* tmp = cur; cur = nxt; nxt = tmp;
    }
    dec_kernel<<<NPIX/256, 256, 0, stream>>>(cur, decdot, flag, d_out);
}